// Round 7
// baseline (10870.599 us; speedup 1.0000x reference)
//
#include <hip/hip_runtime.h>

#define TS    2048
#define BTOT  32
#define IDIM  256
#define HDIM  512
#define GRPS  8      // batch groups (4 batches each)
#define WPG   32     // WGs per group: WG covers 16 h-cols x 4 gates
#define NTHR  256    // 4 waves; wave wv owns hcols wv*4..+3, ALL 4 gates
#define KX    8      // x k-frags (K=256)
#define KT    24     // + 16 h k-frags (K=512)

typedef __attribute__((ext_vector_type(8))) short bfrag;   // 8 bf16
typedef __attribute__((ext_vector_type(4))) float facc;    // 4 f32
typedef unsigned long long u64;

#define LD_A64(p)   __hip_atomic_load((p),  __ATOMIC_RELAXED, __HIP_MEMORY_SCOPE_AGENT)
#define ST_A64(p,v) __hip_atomic_store((p),(v),__ATOMIC_RELAXED, __HIP_MEMORY_SCOPE_AGENT)

__device__ __forceinline__ unsigned short f2bf(float f){
    unsigned u = __builtin_bit_cast(unsigned, f);
    u += 0x7FFFu + ((u >> 16) & 1u);            // RNE
    return (unsigned short)(u >> 16);
}
__device__ __forceinline__ unsigned pack2(float a, float b){
    return (unsigned)f2bf(a) | ((unsigned)f2bf(b) << 16);
}

// Protocol: self-timestamped u64 words (tag|2xbf16), parity double buffer,
// per-word register snapshots (a matched word is never reloaded). Overwrite
// safety: WG publishes tag t+2 only after its B1(t), which requires all its
// waves to have validated ALL 1024 group words at tag t+1; a word carries
// tag t+1 only if its producer passed B1(t-1), i.e. snapshotted every word
// at tag t. So no wanted tag is destroyed before every WG snapshotted it.
// LDS hstage is parity-double-buffered; adjacent-step writes/reads use
// different halves and are separated by B1.
//
// B-col remap: wave wv, lane l15 -> (gate gq=l15&3, hcol=r*16+wv*4+(l15>>2)).
// A-rows batch-replicated: row -> batch row&3, so D row kgrp*4+q -> batch q
// for every kgrp: lane's zz[q] = z[batch q][gq][hcol]. Gate combine = 4
// intra-quad shuffles; NO zfull LDS, NO second barrier.
//
// hstage swizzle (R6 bugfix): write byte (c*16)^(row<<5); read byte for frag
// jj must be (jj*64 + kgrp*16)^(gq<<5). gq<<5 carries bit 6 which overlaps
// jj*64, so the XOR must be applied to the FULL offset: precompute
// hrdbase = gq*1024 + ((kgrp*16)^(gq<<5)) and read at hrdbase ^ (jj*64)
// (equivalent, since the base's bits 6..9 hold only gq>>1).

#define XREFILL(XF_, tn_) do{                                                   \
    _Pragma("unroll")                                                           \
    for (int j = 0; j < KX; ++j){                                               \
      const float4* p4 = reinterpret_cast<const float4*>(                       \
          x + ((size_t)(tn_)*BTOT + xrow)*IDIM + j*32 + kgrp*8);                \
      const float4 f0 = p4[0], f1 = p4[1];                                      \
      bfrag v;                                                                  \
      v[0]=(short)f2bf(f0.x); v[1]=(short)f2bf(f0.y);                           \
      v[2]=(short)f2bf(f0.z); v[3]=(short)f2bf(f0.w);                           \
      v[4]=(short)f2bf(f1.x); v[5]=(short)f2bf(f1.y);                           \
      v[6]=(short)f2bf(f1.z); v[7]=(short)f2bf(f1.w);                           \
      XF_[j] = v;                                                               \
    }                                                                           \
  }while(0)

#define LSTM_STEP(Tt, XF_, TPF_)                                                \
  do {                                                                          \
    facc acc[4];                                                                \
    _Pragma("unroll")                                                           \
    for (int q = 0; q < 4; ++q) acc[q] = (facc){0.f,0.f,0.f,0.f};               \
    /* x-GEMM (overlaps the in-flight tagged h loads issued last tail) */       \
    _Pragma("unroll")                                                           \
    for (int j = 0; j < KX; ++j)                                                \
      acc[j & 3] = __builtin_amdgcn_mfma_f32_16x16x32_bf16(XF_[j], breg[j],     \
                                                           acc[j & 3], 0,0,0); \
    /* tag check + per-word retry (matched words keep register snapshot) */     \
    { const unsigned want = (unsigned)(Tt) + 1u;                                \
      while ((((unsigned)(w0 >> 32) != want) | ((unsigned)(w1 >> 32) != want) | \
              ((unsigned)(w2 >> 32) != want) | ((unsigned)(w3 >> 32) != want))  \
             != 0u){                                                            \
        if ((unsigned)(w0 >> 32) != want) w0 = LD_A64(hsrc + 0);                \
        if ((unsigned)(w1 >> 32) != want) w1 = LD_A64(hsrc + 1);                \
        if ((unsigned)(w2 >> 32) != want) w2 = LD_A64(hsrc + 2);                \
        if ((unsigned)(w3 >> 32) != want) w3 = LD_A64(hsrc + 3);                \
      } }                                                                       \
    /* stage h into XOR-swizzled LDS (double-buffered by parity) */             \
    { uint4 pv; pv.x = (unsigned)w0; pv.y = (unsigned)w1;                       \
      pv.z = (unsigned)w2; pv.w = (unsigned)w3;                                 \
      *reinterpret_cast<uint4*>(                                                \
          reinterpret_cast<char*>(&hstage[(Tt) & 1][0][0]) + stoff) = pv; }     \
    __syncthreads();                                     /* B1 (only barrier) */\
    /* h-GEMM: 16 MFMAs in 4 chains, conflict-free swizzled b128 reads */       \
    { const char* hbase =                                                       \
          reinterpret_cast<const char*>(&hstage[(Tt) & 1][0][0]);               \
      _Pragma("unroll")                                                         \
      for (int jj = 0; jj < 16; ++jj){                                          \
        const bfrag hf = *reinterpret_cast<const bfrag*>(                       \
            hbase + (hrdbase ^ (jj * 64)));                                     \
        acc[jj & 3] = __builtin_amdgcn_mfma_f32_16x16x32_bf16(hf, breg[KX+jj],  \
                                                              acc[jj & 3],     \
                                                              0,0,0);          \
      } }                                                                       \
    const facc zz = (acc[0] + acc[1]) + (acc[2] + acc[3]);                      \
    /* select batch kgrp (static extracts + cndmask), add bias + dt term */     \
    float zq = zz[0];                                                           \
    zq = (kgrp == 1) ? zz[1] : zq;                                              \
    zq = (kgrp == 2) ? zz[2] : zq;                                              \
    zq = (kgrp == 3) ? zz[3] : zq;                                              \
    zq += bsL + wtL * (TPF_);                                                   \
    /* quad broadcast: gather all 4 gates of (batch kgrp, hcol) */              \
    const float zI = __shfl(zq, qb + 0);                                        \
    const float zF = __shfl(zq, qb + 1);                                        \
    const float zG = __shfl(zq, qb + 2);                                        \
    const float zO = __shfl(zq, qb + 3);                                        \
    const float ig = 1.f / (1.f + __expf(-zI));                                 \
    const float fg = 1.f / (1.f + __expf(-zF));                                 \
    const float gg = 1.f - 2.f / (__expf(2.f * zG) + 1.f);                      \
    const float og = 1.f / (1.f + __expf(-zO));                                 \
    creg = fg * creg + ig * gg;                                                 \
    const float hn = og * (1.f - 2.f / (__expf(2.f * creg) + 1.f));             \
    const float hnR = __shfl_xor(hn, 4);            /* neighbor col (c4^1) */   \
    if (pubL)                                                                   \
      ST_A64(hgrp + (size_t)(((Tt) + 1) & 1) * 1024 + kgrp * 256 + (hcol >> 1), \
             ((u64)((unsigned)(Tt) + 2u) << 32) | (u64)pack2(hn, hnR));         \
    /* ---- tail: issue next h loads FIRST (FIFO), then x, then out ---- */     \
    { const int tn = ((Tt) + 2 < TS) ? ((Tt) + 2) : (TS - 1);                   \
      hsrc = hgrp + (size_t)(((Tt) + 1) & 1) * 1024 + (size_t)tid * 4;          \
      w0 = LD_A64(hsrc + 0); w1 = LD_A64(hsrc + 1);                             \
      w2 = LD_A64(hsrc + 2); w3 = LD_A64(hsrc + 3);                             \
      XREFILL(XF_, tn);                                                         \
      (TPF_) = tim[(size_t)tn * BTOT + bglob];                                  \
      if (pubL)                                                                 \
        *reinterpret_cast<float2*>(                                             \
            &out[((size_t)(Tt) * BTOT + bglob) * HDIM + hcol]) =                \
            make_float2(hn, hnR);                                               \
      if ((Tt) == TS - 1){                                                      \
        const float cR = __shfl_xor(creg, 4);                                   \
        if (pubL){                                                              \
          float* hT = out + (size_t)TS * BTOT * HDIM;                           \
          float* cT = hT + (size_t)BTOT * HDIM;                                 \
          *reinterpret_cast<float2*>(&hT[(size_t)bglob * HDIM + hcol]) =        \
              make_float2(hn, hnR);                                             \
          *reinterpret_cast<float2*>(&cT[(size_t)bglob * HDIM + hcol]) =        \
              make_float2(creg, cR);                                            \
        }                                                                       \
      }                                                                         \
    }                                                                           \
  } while(0)

__global__ __launch_bounds__(NTHR, 1) void lstm_bfly(
    const float* __restrict__ x,      // [T,B,I]
    const float* __restrict__ tim,    // [T,B,1]
    const float* __restrict__ Wih,    // [4H, I+1]
    const float* __restrict__ Whh,    // [4H, H]
    const float* __restrict__ bias,   // [4H]
    const float* __restrict__ h0,     // [B,H]
    const float* __restrict__ c0,     // [B,H]
    float* __restrict__ out,          // [T,B,H] ++ [B,H] ++ [B,H]
    u64* __restrict__ hbuf)           // [GRPS][2][1024] tagged words
{
    const int tid = threadIdx.x, bid = blockIdx.x;
    const int g = bid & 7, r = bid >> 3;           // group, 16-col role
    const int wv = tid >> 6, lane = tid & 63, l15 = lane & 15, kgrp = lane >> 4;

    const int gq   = l15 & 3;                      // gate of this lane
    const int c4   = l15 >> 2;                     // col-in-wave 0..3
    const int hcol = r * 16 + wv * 4 + c4;
    const int bglob = g * 4 + kgrp;                // batch on the D/gate side
    const int xrow  = g * 4 + gq;                  // batch on the A-row side
    const int qb    = lane & ~3;                   // quad base for shuffles
    const bool pubL = (l15 == 0) || (l15 == 8);    // c4 even && gq==0

    __shared__ unsigned short hstage[2][4][512];   // 8 KB, XOR-swizzled rows

    u64* hgrp = hbuf + (size_t)g * 2048;

    // ---- weights in registers: col l15 -> W[gq*H + hcol], full K ----
    bfrag breg[KT];
    const int colg = gq * HDIM + hcol;
    #pragma unroll
    for (int j = 0; j < KT; ++j){
        const float* src = (j < KX)
            ? (Wih + (size_t)colg * (IDIM + 1) + j * 32 + kgrp * 8)
            : (Whh + (size_t)colg * HDIM + (j - KX) * 32 + kgrp * 8);
        bfrag v;
        #pragma unroll
        for (int q = 0; q < 8; ++q) v[q] = (short)f2bf(src[q]);
        breg[j] = v;
    }

    // ---- per-lane gate constants + c state (quad-redundant, deterministic) --
    const float bsL = bias[colg];
    const float wtL = Wih[(size_t)colg * (IDIM + 1) + IDIM];  // dt column
    float creg = c0[(size_t)bglob * HDIM + hcol];

    // ---- publish h(0): parity 0, tag 1 ----
    if (pubL)
        ST_A64(hgrp + 0 * 1024 + kgrp * 256 + (hcol >> 1),
               (1ULL << 32) | (u64)pack2(h0[(size_t)bglob * HDIM + hcol],
                                         h0[(size_t)bglob * HDIM + hcol + 1]));

    // ---- staging offsets (thread owns words tid*4..+3 = batch tid>>6) ----
    const int swb   = tid >> 6;
    const int stoff = swb * 1024 + (((tid & 63) * 16) ^ (swb << 5));
    // MFMA read base: row gq, k-slice kgrp, swizzled; frag jj at base^(jj*64)
    const int hrdbase = gq * 1024 + ((kgrp * 16) ^ (gq << 5));

    // ---- issue initial tagged loads (parity 0) BEFORE the x prefetch ----
    const u64* hsrc = hgrp + (size_t)tid * 4;
    u64 w0 = LD_A64(hsrc + 0), w1 = LD_A64(hsrc + 1);
    u64 w2 = LD_A64(hsrc + 2), w3 = LD_A64(hsrc + 3);

    // ---- x prefetch (all lanes; rows batch-replicated), time prefetch ----
    bfrag xe[KX], xo[KX];
    XREFILL(xe, 0);
    XREFILL(xo, 1);
    float tpe = tim[(size_t)0 * BTOT + bglob];
    float tpo = tim[(size_t)1 * BTOT + bglob];

    for (int t = 0; t < TS; t += 2){
        LSTM_STEP(t,     xe, tpe);
        LSTM_STEP(t + 1, xo, tpo);
    }
}

extern "C" void kernel_launch(void* const* d_in, const int* in_sizes, int n_in,
                              void* d_out, int out_size, void* d_ws, size_t ws_size,
                              hipStream_t stream) {
    const float* x    = (const float*)d_in[0];
    const float* tim  = (const float*)d_in[1];
    const float* Wih  = (const float*)d_in[2];
    const float* Whh  = (const float*)d_in[3];
    const float* bias = (const float*)d_in[4];
    const float* h0   = (const float*)d_in[5];
    const float* c0   = (const float*)d_in[6];

    u64* hbuf = (u64*)d_ws;

    // tags must start != any wanted tag every launch (graph replays included)
    hipMemsetAsync(d_ws, 0, GRPS * 2 * 1024 * sizeof(u64), stream);

    lstm_bfly<<<GRPS * WPG, NTHR, 0, stream>>>(x, tim, Wih, Whh, bias, h0, c0,
                                               (float*)d_out, hbuf);
}

// Round 8
// 9957.250 us; speedup vs baseline: 1.0917x; 1.0917x over previous
//
#include <hip/hip_runtime.h>

#define TS    2048
#define BTOT  32
#define IDIM  256
#define HDIM  512
#define GRPS  8      // batch groups (4 batches each); h exchanged only in-group
#define WPG   32     // WGs per group: 64 gate cols each (16 h-cols x 4 gates)
#define BPG   4
#define NTHR  256    // 4 waves; wave wv = gate wv (N-split, full K)
#define KX    8      // x k-frags (K=256)
#define KT    24     // + 16 h k-frags (K=512)

typedef __attribute__((ext_vector_type(8))) short bfrag;   // 8 bf16
typedef __attribute__((ext_vector_type(4))) float facc;    // 4 f32
typedef unsigned long long u64;

#define LD_A64(p)   __hip_atomic_load((p),  __ATOMIC_RELAXED, __HIP_MEMORY_SCOPE_AGENT)
#define ST_A64(p,v) __hip_atomic_store((p),(v),__ATOMIC_RELAXED, __HIP_MEMORY_SCOPE_AGENT)

__device__ __forceinline__ unsigned short f2bf(float f){
    unsigned u = __builtin_bit_cast(unsigned, f);
    u += 0x7FFFu + ((u >> 16) & 1u);            // RNE
    return (unsigned short)(u >> 16);
}
__device__ __forceinline__ unsigned pack2(float a, float b){
    return (unsigned)f2bf(a) | ((unsigned)f2bf(b) << 16);
}

// Protocol: self-timestamped u64 words (tag<<32 | 2xbf16), parity double
// buffer, per-word register snapshots. Overwrite safety: a WG publishes tag
// t+2 only after its B1(t), which requires all its waves to have snapshotted
// ALL 1024 group words at tag t+1; a word carries tag t+1 only if its
// producer passed B1(t-1). So no wanted tag is destroyed before every WG
// snapshotted it. hbuf memset to 0 each launch -> graph replays deterministic.
//
// hstage: [2 parity][4 batch][512] bf16, R7-VERIFIED swizzle (0 conflicts):
//   write byte = row*1024 + (((tid&63)*16) ^ (row<<5))
//   read  byte = hrdbase ^ (j*64), hrdbase = row*1024 + ((kgrp*16)^(row<<5))
// (XOR applied to the full offset; (row<<5) bit6 overlaps j*64 — R6 lesson.)
//
// Epilogue: wave wv owns batch wv; lanes 0..7 handle 2 cols each. Publishes
// are 8 consecutive u64 = 64 B per wave (coalesced; R7's scatter regression
// avoided). out stores after the publish, 64 B contiguous per wave.

#define XREFILL(XF_, tn_) do{                                                   \
    if (ldr){                                                                   \
      _Pragma("unroll")                                                         \
      for (int j = 0; j < KX; ++j){                                             \
        const float4* p4 = reinterpret_cast<const float4*>(                     \
            x + ((size_t)(tn_)*BTOT + lbg)*IDIM + j*32 + kgrp*8);               \
        const float4 f0 = p4[0], f1 = p4[1];                                    \
        bfrag v;                                                                \
        v[0]=(short)f2bf(f0.x); v[1]=(short)f2bf(f0.y);                         \
        v[2]=(short)f2bf(f0.z); v[3]=(short)f2bf(f0.w);                         \
        v[4]=(short)f2bf(f1.x); v[5]=(short)f2bf(f1.y);                         \
        v[6]=(short)f2bf(f1.z); v[7]=(short)f2bf(f1.w);                         \
        XF_[j] = v;                                                             \
      }                                                                         \
    }                                                                           \
  }while(0)

#define LSTM_STEP(Tt, XF_, TPF_)                                                \
  do {                                                                          \
    facc acc[4];                                                                \
    _Pragma("unroll")                                                           \
    for (int q = 0; q < 4; ++q) acc[q] = (facc){0.f,0.f,0.f,0.f};               \
    /* x-GEMM overlaps the in-flight tagged h loads (issued last tail) */       \
    _Pragma("unroll")                                                           \
    for (int j = 0; j < KX; ++j)                                                \
      acc[j & 3] = __builtin_amdgcn_mfma_f32_16x16x32_bf16(XF_[j], breg[j],     \
                                                           acc[j & 3], 0,0,0); \
    /* poll w0 only (w0..w3 share the producer's 64B store run), then rest */   \
    { const unsigned want = (unsigned)(Tt) + 1u;                                \
      while ((unsigned)(w0 >> 32) != want) w0 = LD_A64(hsrc + 0);               \
      while ((((unsigned)(w1 >> 32) != want) | ((unsigned)(w2 >> 32) != want) | \
              ((unsigned)(w3 >> 32) != want)) != 0u){                           \
        if ((unsigned)(w1 >> 32) != want) w1 = LD_A64(hsrc + 1);                \
        if ((unsigned)(w2 >> 32) != want) w2 = LD_A64(hsrc + 2);                \
        if ((unsigned)(w3 >> 32) != want) w3 = LD_A64(hsrc + 3);                \
      } }                                                                       \
    /* stage h into swizzled LDS (parity double buffer) */                      \
    { uint4 pv; pv.x = (unsigned)w0; pv.y = (unsigned)w1;                       \
      pv.z = (unsigned)w2; pv.w = (unsigned)w3;                                 \
      *reinterpret_cast<uint4*>(                                                \
          reinterpret_cast<char*>(&hstage[(Tt) & 1][0][0]) + stoff) = pv; }     \
    __syncthreads();                                     /* B1 */               \
    /* h-GEMM: 16 MFMAs in 4 chains, 0-conflict swizzled b128 reads */          \
    { const char* hbase =                                                       \
          reinterpret_cast<const char*>(&hstage[(Tt) & 1][0][0]);               \
      _Pragma("unroll")                                                         \
      for (int jj = 0; jj < 16; ++jj){                                          \
        const bfrag hf = *reinterpret_cast<const bfrag*>(                       \
            hbase + (hrdbase ^ (jj * 64)));                                     \
        acc[jj & 3] = __builtin_amdgcn_mfma_f32_16x16x32_bf16(hf, breg[KX+jj],  \
                                                              acc[jj & 3],     \
                                                              0,0,0);          \
      } }                                                                       \
    const facc zz = (acc[0] + acc[1]) + (acc[2] + acc[3]);                      \
    if (lane < 16){   /* D rows 0..3 = batches (rows 4..15 junk, never read) */ \
      _Pragma("unroll")                                                         \
      for (int q = 0; q < 4; ++q) zfull[wv][q][lane] = zz[q];                   \
    }                                                                           \
    __syncthreads();                                     /* B2 */               \
    /* per-wave epilogue: wave wv = batch wv, lanes 0..7, 2 cols each */        \
    float hn0 = 0.f, hn1 = 0.f;                                                 \
    if (lane < 8){                                                              \
      float zg0[4], zg1[4];                                                     \
      _Pragma("unroll")                                                         \
      for (int gt = 0; gt < 4; ++gt){                                           \
        const float2 zp = *reinterpret_cast<const float2*>(                     \
            &zfull[gt][wv][2 * lane]);                                          \
        zg0[gt] = zp.x + bs2[gt][0] + wt2[gt][0] * (TPF_);                      \
        zg1[gt] = zp.y + bs2[gt][1] + wt2[gt][1] * (TPF_);                      \
      }                                                                         \
      { const float ig = 1.f/(1.f+__expf(-zg0[0]));                             \
        const float fg = 1.f/(1.f+__expf(-zg0[1]));                             \
        const float gg = 1.f - 2.f/(__expf(2.f*zg0[2])+1.f);                    \
        const float og = 1.f/(1.f+__expf(-zg0[3]));                             \
        creg0 = fg*creg0 + ig*gg;                                               \
        hn0 = og*(1.f - 2.f/(__expf(2.f*creg0)+1.f)); }                         \
      { const float ig = 1.f/(1.f+__expf(-zg1[0]));                             \
        const float fg = 1.f/(1.f+__expf(-zg1[1]));                             \
        const float gg = 1.f - 2.f/(__expf(2.f*zg1[2])+1.f);                    \
        const float og = 1.f/(1.f+__expf(-zg1[3]));                             \
        creg1 = fg*creg1 + ig*gg;                                               \
        hn1 = og*(1.f - 2.f/(__expf(2.f*creg1)+1.f)); }                         \
      ST_A64(hgrp + (size_t)(((Tt)+1) & 1) * 1024 + wv * 256 + r * 8 + lane,    \
             ((u64)((unsigned)(Tt) + 2u) << 32) | (u64)pack2(hn0, hn1));        \
    }                                                                           \
    /* ---- tail: issue next tagged loads FIRST, then x, then out ---- */       \
    { const int tn = ((Tt) + 2 < TS) ? ((Tt) + 2) : (TS - 1);                   \
      hsrc = hgrp + (size_t)(((Tt) + 1) & 1) * 1024 + (size_t)tid * 4;          \
      w0 = LD_A64(hsrc + 0); w1 = LD_A64(hsrc + 1);                             \
      w2 = LD_A64(hsrc + 2); w3 = LD_A64(hsrc + 3);                             \
      XREFILL(XF_, tn);                                                         \
      if (lane < 8){                                                            \
        (TPF_) = tim[(size_t)tn * BTOT + bglob];                                \
        *reinterpret_cast<float2*>(                                             \
            &out[((size_t)(Tt) * BTOT + bglob) * HDIM + hcol0]) =               \
            make_float2(hn0, hn1);                                              \
        if ((Tt) == TS - 1){                                                    \
          float* hT = out + (size_t)TS * BTOT * HDIM;                           \
          float* cT = hT + (size_t)BTOT * HDIM;                                 \
          *reinterpret_cast<float2*>(&hT[(size_t)bglob * HDIM + hcol0]) =       \
              make_float2(hn0, hn1);                                            \
          *reinterpret_cast<float2*>(&cT[(size_t)bglob * HDIM + hcol0]) =       \
              make_float2(creg0, creg1);                                        \
        }                                                                       \
      }                                                                         \
    }                                                                           \
  } while(0)

__global__ __launch_bounds__(NTHR, 1) void lstm_wave(
    const float* __restrict__ x,      // [T,B,I]
    const float* __restrict__ tim,    // [T,B,1]
    const float* __restrict__ Wih,    // [4H, I+1]
    const float* __restrict__ Whh,    // [4H, H]
    const float* __restrict__ bias,   // [4H]
    const float* __restrict__ h0,     // [B,H]
    const float* __restrict__ c0,     // [B,H]
    float* __restrict__ out,          // [T,B,H] ++ [B,H] ++ [B,H]
    u64* __restrict__ hbuf)           // [GRPS][2][1024] tagged words
{
    const int tid = threadIdx.x, bid = blockIdx.x;
    const int g = bid & 7, r = bid >> 3;           // group, 16-col role
    const int wv = tid >> 6, lane = tid & 63, l15 = lane & 15, kgrp = lane >> 4;

    __shared__ unsigned short hstage[2][4][512];   // 8 KB, swizzled
    __shared__ float zfull[4][4][16];              // [gate][batch][col]

    u64* hgrp = hbuf + (size_t)g * 2048;

    // ---- weights in registers: wave wv = gate wv, cols r*16+l15, full K ----
    bfrag breg[KT];
    {
        const int colg = wv * HDIM + r * 16 + l15;
        #pragma unroll
        for (int j = 0; j < KT; ++j){
            const float* src = (j < KX)
                ? (Wih + (size_t)colg * (IDIM + 1) + j * 32 + kgrp * 8)
                : (Whh + (size_t)colg * HDIM + (j - KX) * 32 + kgrp * 8);
            bfrag v;
            #pragma unroll
            for (int q = 0; q < 8; ++q) v[q] = (short)f2bf(src[q]);
            breg[j] = v;
        }
    }

    // ---- epilogue constants: wave wv = batch wv, lanes 0..7, 2 cols ----
    const int hcol0 = r * 16 + 2 * lane;           // valid for lane<8
    const int bglob = g * BPG + wv;
    float bs2[4][2], wt2[4][2];
    float creg0 = 0.f, creg1 = 0.f;
    if (lane < 8){
        #pragma unroll
        for (int gt = 0; gt < 4; ++gt){
            const size_t cg = (size_t)gt * HDIM + hcol0;
            bs2[gt][0] = bias[cg];     bs2[gt][1] = bias[cg + 1];
            wt2[gt][0] = Wih[cg * (IDIM + 1) + IDIM];
            wt2[gt][1] = Wih[(cg + 1) * (IDIM + 1) + IDIM];
        }
        creg0 = c0[(size_t)bglob * HDIM + hcol0];
        creg1 = c0[(size_t)bglob * HDIM + hcol0 + 1];
        // publish h(0): parity 0, tag 1 (64 B contiguous per wave)
        ST_A64(hgrp + 0 * 1024 + wv * 256 + r * 8 + lane,
               (1ULL << 32) | (u64)pack2(h0[(size_t)bglob * HDIM + hcol0],
                                         h0[(size_t)bglob * HDIM + hcol0 + 1]));
    } else {
        #pragma unroll
        for (int gt = 0; gt < 4; ++gt){
            bs2[gt][0] = bs2[gt][1] = wt2[gt][0] = wt2[gt][1] = 0.f;
        }
    }

    // ---- staging / read offsets (R7-verified swizzle) ----
    const int swb   = tid >> 6;                    // staged batch row
    const int stoff = swb * 1024 + (((tid & 63) * 16) ^ (swb << 5));
    const int lb    = l15 & 3;                     // A-row batch
    const int hrdbase = lb * 1024 + ((kgrp * 16) ^ (lb << 5));

    // ---- A-loader lanes for x (rows 0..3 real, 4..15 junk) ----
    const bool ldr = (l15 < 4);
    const int lbg = g * BPG + lb;

    // ---- issue initial tagged loads (parity 0) BEFORE the x prefetch ----
    const u64* hsrc = hgrp + (size_t)tid * 4;
    u64 w0 = LD_A64(hsrc + 0), w1 = LD_A64(hsrc + 1);
    u64 w2 = LD_A64(hsrc + 2), w3 = LD_A64(hsrc + 3);

    // ---- x prefetch x(0)->xe, x(1)->xo; time prefetch ----
    bfrag xe[KX], xo[KX];
    #pragma unroll
    for (int j = 0; j < KX; ++j){
        bfrag zv;
        #pragma unroll
        for (int q = 0; q < 8; ++q) zv[q] = 0;
        xe[j] = zv; xo[j] = zv;
    }
    XREFILL(xe, 0);
    XREFILL(xo, 1);
    float tpe = 0.f, tpo = 0.f;
    if (lane < 8){
        tpe = tim[(size_t)0 * BTOT + bglob];
        tpo = tim[(size_t)1 * BTOT + bglob];
    }

    for (int t = 0; t < TS; t += 2){
        LSTM_STEP(t,     xe, tpe);
        LSTM_STEP(t + 1, xo, tpo);
    }
}

extern "C" void kernel_launch(void* const* d_in, const int* in_sizes, int n_in,
                              void* d_out, int out_size, void* d_ws, size_t ws_size,
                              hipStream_t stream) {
    const float* x    = (const float*)d_in[0];
    const float* tim  = (const float*)d_in[1];
    const float* Wih  = (const float*)d_in[2];
    const float* Whh  = (const float*)d_in[3];
    const float* bias = (const float*)d_in[4];
    const float* h0   = (const float*)d_in[5];
    const float* c0   = (const float*)d_in[6];

    u64* hbuf = (u64*)d_ws;

    // tags must start != any wanted tag every launch (graph replays included)
    hipMemsetAsync(d_ws, 0, GRPS * 2 * 1024 * sizeof(u64), stream);

    lstm_wave<<<GRPS * WPG, NTHR, 0, stream>>>(x, tim, Wih, Whh, bias, h0, c0,
                                               (float*)d_out, hbuf);
}

// Round 9
// 8002.921 us; speedup vs baseline: 1.3583x; 1.2442x over previous
//
#include <hip/hip_runtime.h>

#define TS    2048
#define BTOT  32
#define IDIM  256
#define HDIM  512
#define GRPS  8      // batch groups (4 batches each); h exchanged only in-group
#define WPG   32     // WGs per group: 64 gate cols each (16 h-cols x 4 gates)
#define BPG   4
#define NTHR  256    // 4 waves; wave wv = gate wv (N-split, full K)
#define KX    8      // x k-frags (K=256)
#define KT    24     // + 16 h k-frags (K=512)

typedef __attribute__((ext_vector_type(8))) short    bfrag;  // 8 bf16
typedef __attribute__((ext_vector_type(4))) float    facc;   // 4 f32
typedef unsigned long long u64;

#define LD_A64(p)   __hip_atomic_load((p),  __ATOMIC_RELAXED, __HIP_MEMORY_SCOPE_AGENT)
#define ST_A64(p,v) __hip_atomic_store((p),(v),__ATOMIC_RELAXED, __HIP_MEMORY_SCOPE_AGENT)

__device__ __forceinline__ unsigned short f2bf(float f){
    unsigned u = __builtin_bit_cast(unsigned, f);
    u += 0x7FFFu + ((u >> 16) & 1u);            // RNE
    return (unsigned short)(u >> 16);
}
__device__ __forceinline__ unsigned pack2(float a, float b){
    return (unsigned)f2bf(a) | ((unsigned)f2bf(b) << 16);
}

// R5 skeleton (6.78 ms champion) + ONLY:
//  (1) s_sleep(1) backoff in the tag-retry loop (cuts poll contention on the
//      32 hot hbuf lines per group; detection load then sees a quiet fabric)
//  (2) R7/R8-verified 0-conflict LDS hstage swizzle (parity double buffer):
//      write byte = row*1024 + ((chunk*16) ^ (row<<5))
//      read  byte = hrdbase ^ (j*64),  hrdbase = lb*1024 + ((kgrp*16)^(lb<<5))
//      (XOR on the FULL offset: (row<<5) bit6 overlaps j*64 — R6 lesson.)
// Protocol unchanged: self-timestamped u64 words (tag<<32 | 2xbf16), parity
// double buffer, per-word register snapshots; overwrite safety via B1-chain
// (see R5 notes). hbuf memset each launch -> graph replays deterministic.

#define LSTM_STEP(Tt, XF, TPF)                                                  \
  do {                                                                          \
    facc ze = {0.f,0.f,0.f,0.f}, zo = {0.f,0.f,0.f,0.f};                        \
    /* x-GEMM overlaps the in-flight tagged h loads (issued last tail) */       \
    _Pragma("unroll")                                                           \
    for (int j = 0; j < KX; j += 2){                                            \
      ze = __builtin_amdgcn_mfma_f32_16x16x32_bf16(XF[j],   breg[j],   ze,0,0,0); \
      zo = __builtin_amdgcn_mfma_f32_16x16x32_bf16(XF[j+1], breg[j+1], zo,0,0,0); \
    }                                                                           \
    /* tag check + retry with s_sleep backoff (matched words keep snapshot) */  \
    { const unsigned want = (unsigned)(Tt) + 1u;                                \
      while ((((unsigned)(w0 >> 32) != want) | ((unsigned)(w1 >> 32) != want) | \
              ((unsigned)(w2 >> 32) != want) | ((unsigned)(w3 >> 32) != want))  \
             != 0u){                                                            \
        __builtin_amdgcn_s_sleep(1);                                            \
        if ((unsigned)(w0 >> 32) != want) w0 = LD_A64(hsrc + 0);                \
        if ((unsigned)(w1 >> 32) != want) w1 = LD_A64(hsrc + 1);                \
        if ((unsigned)(w2 >> 32) != want) w2 = LD_A64(hsrc + 2);                \
        if ((unsigned)(w3 >> 32) != want) w3 = LD_A64(hsrc + 3);                \
      } }                                                                       \
    /* stage h into swizzled LDS (parity double buffer) */                      \
    { uint4 pv; pv.x = (unsigned)w0; pv.y = (unsigned)w1;                       \
      pv.z = (unsigned)w2; pv.w = (unsigned)w3;                                 \
      *reinterpret_cast<uint4*>(                                                \
          reinterpret_cast<char*>(&hstage[(Tt) & 1][0][0]) + stoff) = pv; }     \
    __syncthreads();                                  /* B1: h staged */        \
    /* h-GEMM: 0-conflict swizzled b128 reads, 2 chains (R5 structure) */       \
    { const char* hb8 =                                                         \
          reinterpret_cast<const char*>(&hstage[(Tt) & 1][0][0]);               \
      _Pragma("unroll")                                                         \
      for (int j = 0; j < 16; j += 2){                                          \
        const bfrag ha = *reinterpret_cast<const bfrag*>(                       \
            hb8 + (hrdbase ^ (j * 64)));                                        \
        const bfrag hbf = *reinterpret_cast<const bfrag*>(                      \
            hb8 + (hrdbase ^ ((j + 1) * 64)));                                  \
        ze = __builtin_amdgcn_mfma_f32_16x16x32_bf16(ha,  breg[KX+j],   ze,0,0,0); \
        zo = __builtin_amdgcn_mfma_f32_16x16x32_bf16(hbf, breg[KX+j+1], zo,0,0,0); \
      } }                                                                       \
    const facc zz = ze + zo;                                                    \
    if (lane < 16){   /* D rows 0..3 = batches (rows 4..15 junk, never read) */ \
      _Pragma("unroll")                                                         \
      for (int q = 0; q < 4; ++q) zfull[wv][q][lane] = zz[q];                   \
    }                                                                           \
    __syncthreads();                                  /* B2: z ready */         \
    float hn0 = 0.f, hn1 = 0.f;                                                 \
    if (gth){                                                                   \
      float zg0[4], zg1[4];                                                     \
      _Pragma("unroll")                                                         \
      for (int gt = 0; gt < 4; ++gt){                                           \
        zg0[gt] = zfull[gt][b][col0]     + bs2[gt][0] + wt2[gt][0] * (TPF);     \
        zg1[gt] = zfull[gt][b][col0 + 1] + bs2[gt][1] + wt2[gt][1] * (TPF);     \
      }                                                                         \
      { const float ig = 1.f/(1.f+__expf(-zg0[0]));                             \
        const float fg = 1.f/(1.f+__expf(-zg0[1]));                             \
        const float gg = 1.f - 2.f/(__expf(2.f*zg0[2])+1.f);                    \
        const float og = 1.f/(1.f+__expf(-zg0[3]));                             \
        creg0 = fg*creg0 + ig*gg;                                               \
        hn0 = og*(1.f - 2.f/(__expf(2.f*creg0)+1.f)); }                         \
      { const float ig = 1.f/(1.f+__expf(-zg1[0]));                             \
        const float fg = 1.f/(1.f+__expf(-zg1[1]));                             \
        const float gg = 1.f - 2.f/(__expf(2.f*zg1[2])+1.f);                    \
        const float og = 1.f/(1.f+__expf(-zg1[3]));                             \
        creg1 = fg*creg1 + ig*gg;                                               \
        hn1 = og*(1.f - 2.f/(__expf(2.f*creg1)+1.f)); }                         \
      ST_A64(hgrp + (size_t)(((Tt)+1) & 1) * 1024 + b*256 + r*8 + cp,           \
             ((u64)((unsigned)(Tt) + 2u) << 32) | (u64)pack2(hn0, hn1));        \
    }                                                                           \
    /* ---- tail: issue next h loads FIRST (FIFO), then x, then out ---- */     \
    { const int tn = ((Tt)+2 < TS) ? ((Tt)+2) : (TS-1);                         \
      hsrc = hgrp + (size_t)(((Tt) + 1) & 1) * 1024 + (size_t)tid * 4;          \
      w0 = LD_A64(hsrc + 0); w1 = LD_A64(hsrc + 1);                             \
      w2 = LD_A64(hsrc + 2); w3 = LD_A64(hsrc + 3);                             \
      if (ldr){                                                                 \
        _Pragma("unroll")                                                       \
        for (int j = 0; j < KX; ++j){                                           \
          const float4* p4 = reinterpret_cast<const float4*>(                   \
              x + ((size_t)tn*BTOT + lbg)*IDIM + j*32 + kgrp*8);                \
          const float4 f0 = p4[0], f1 = p4[1];                                  \
          bfrag v;                                                              \
          v[0]=(short)f2bf(f0.x); v[1]=(short)f2bf(f0.y);                       \
          v[2]=(short)f2bf(f0.z); v[3]=(short)f2bf(f0.w);                       \
          v[4]=(short)f2bf(f1.x); v[5]=(short)f2bf(f1.y);                       \
          v[6]=(short)f2bf(f1.z); v[7]=(short)f2bf(f1.w);                       \
          XF[j] = v;                                                            \
        }                                                                       \
      }                                                                         \
      if (gth){                                                                 \
        (TPF) = tim[(size_t)tn * BTOT + bglob];                                 \
        *reinterpret_cast<float2*>(                                             \
            &out[((size_t)(Tt) * BTOT + bglob) * HDIM + hcol0]) =               \
            make_float2(hn0, hn1);                                              \
        if ((Tt) == TS - 1){                                                    \
          float* hT = out + (size_t)TS * BTOT * HDIM;                           \
          float* cT = hT + (size_t)BTOT * HDIM;                                 \
          *reinterpret_cast<float2*>(&hT[(size_t)bglob * HDIM + hcol0]) =       \
              make_float2(hn0, hn1);                                            \
          *reinterpret_cast<float2*>(&cT[(size_t)bglob * HDIM + hcol0]) =       \
              make_float2(creg0, creg1);                                        \
        }                                                                       \
      }                                                                         \
    }                                                                           \
  } while(0)

__global__ __launch_bounds__(NTHR, 1) void lstm_grp2(
    const float* __restrict__ x,      // [T,B,I]
    const float* __restrict__ tim,    // [T,B,1]
    const float* __restrict__ Wih,    // [4H, I+1]
    const float* __restrict__ Whh,    // [4H, H]
    const float* __restrict__ bias,   // [4H]
    const float* __restrict__ h0,     // [B,H]
    const float* __restrict__ c0,     // [B,H]
    float* __restrict__ out,          // [T,B,H] ++ [B,H] ++ [B,H]
    u64* __restrict__ hbuf)           // [GRPS][2][1024] tagged words
{
    const int tid = threadIdx.x, bid = blockIdx.x;
    const int g = bid & 7, r = bid >> 3;           // group, 16-col role
    const int wv = tid >> 6, lane = tid & 63, l15 = lane & 15, kgrp = lane >> 4;

    __shared__ unsigned short hstage[2][4][512];   // 8 KB, swizzled (R7-verified)
    __shared__ float zfull[4][4][16];              // [gate][b][col]

    u64* hgrp = hbuf + (size_t)g * 2048;

    // ---- weights in registers: wave wv = gate wv, cols r*16+l15, full K ----
    bfrag breg[KT];
    {
        const int colg = wv * HDIM + r * 16 + l15;
        #pragma unroll
        for (int j = 0; j < KT; ++j){
            const float* src = (j < KX)
                ? (Wih + (size_t)colg * (IDIM + 1) + j * 32 + kgrp * 8)
                : (Whh + (size_t)colg * HDIM + (j - KX) * 32 + kgrp * 8);
            bfrag v;
            #pragma unroll
            for (int q = 0; q < 8; ++q) v[q] = (short)f2bf(src[q]);
            breg[j] = v;
        }
    }

    // ---- gate threads (tid<32): item (b, col0=2*cp, col0+1) ----
    const bool gth = (tid < 32);
    const int b = (tid >> 3) & 3, cp = tid & 7, col0 = cp * 2;
    const int hcol0 = r * 16 + col0, bglob = g * BPG + b;
    float bs2[4][2], wt2[4][2];
    float creg0 = 0.f, creg1 = 0.f;
    if (gth){
        #pragma unroll
        for (int gt = 0; gt < 4; ++gt){
            const size_t cg = (size_t)gt * HDIM + hcol0;
            bs2[gt][0] = bias[cg];     bs2[gt][1] = bias[cg + 1];
            wt2[gt][0] = Wih[cg * (IDIM + 1) + IDIM];
            wt2[gt][1] = Wih[(cg + 1) * (IDIM + 1) + IDIM];
        }
        creg0 = c0[(size_t)bglob * HDIM + hcol0];
        creg1 = c0[(size_t)bglob * HDIM + hcol0 + 1];
        // publish h(0): parity 0, tag 1
        ST_A64(hgrp + 0 * 1024 + b * 256 + r * 8 + cp,
               (1ULL << 32) | (u64)pack2(h0[(size_t)bglob * HDIM + hcol0],
                                         h0[(size_t)bglob * HDIM + hcol0 + 1]));
    } else {
        #pragma unroll
        for (int gt = 0; gt < 4; ++gt){
            bs2[gt][0] = bs2[gt][1] = wt2[gt][0] = wt2[gt][1] = 0.f;
        }
    }

    // ---- staging / read offsets (R7/R8-verified 0-conflict swizzle) ----
    const int swb   = tid >> 6;                     // staged batch row
    const int stoff = swb * 1024 + (((tid & 63) * 16) ^ (swb << 5));
    const int lb    = l15 & 3;                      // A-row batch
    const int hrdbase = lb * 1024 + ((kgrp * 16) ^ (lb << 5));

    // ---- A-loader lanes for x (rows 0..3 real, 4..15 junk) ----
    const bool ldr = (l15 < 4);
    const int lbg = g * BPG + lb;

    // ---- issue initial tagged loads (parity 0) BEFORE the x prefetch ----
    const u64* hsrc = hgrp + (size_t)tid * 4;
    u64 w0 = LD_A64(hsrc + 0), w1 = LD_A64(hsrc + 1);
    u64 w2 = LD_A64(hsrc + 2), w3 = LD_A64(hsrc + 3);

    // ---- x prefetch x(0)->xe, x(1)->xo (bf16, registers); time prefetch ----
    bfrag xe[KX], xo[KX];
    #pragma unroll
    for (int j = 0; j < KX; ++j){
        bfrag zv;
        #pragma unroll
        for (int q = 0; q < 8; ++q) zv[q] = 0;
        xe[j] = zv; xo[j] = zv;
    }
    if (ldr){
        #pragma unroll
        for (int j = 0; j < KX; ++j){
            const float4* p0 = reinterpret_cast<const float4*>(
                x + ((size_t)0 * BTOT + lbg) * IDIM + j * 32 + kgrp * 8);
            const float4* p1 = reinterpret_cast<const float4*>(
                x + ((size_t)1 * BTOT + lbg) * IDIM + j * 32 + kgrp * 8);
            const float4 a0 = p0[0], a1 = p0[1], b0 = p1[0], b1 = p1[1];
            bfrag v;
            v[0]=(short)f2bf(a0.x); v[1]=(short)f2bf(a0.y);
            v[2]=(short)f2bf(a0.z); v[3]=(short)f2bf(a0.w);
            v[4]=(short)f2bf(a1.x); v[5]=(short)f2bf(a1.y);
            v[6]=(short)f2bf(a1.z); v[7]=(short)f2bf(a1.w);
            xe[j] = v;
            bfrag w;
            w[0]=(short)f2bf(b0.x); w[1]=(short)f2bf(b0.y);
            w[2]=(short)f2bf(b0.z); w[3]=(short)f2bf(b0.w);
            w[4]=(short)f2bf(b1.x); w[5]=(short)f2bf(b1.y);
            w[6]=(short)f2bf(b1.z); w[7]=(short)f2bf(b1.w);
            xo[j] = w;
        }
    }
    float tpe = 0.f, tpo = 0.f;
    if (gth){
        tpe = tim[(size_t)0 * BTOT + bglob];
        tpo = tim[(size_t)1 * BTOT + bglob];
    }

    for (int t = 0; t < TS; t += 2){
        LSTM_STEP(t,     xe, tpe);
        LSTM_STEP(t + 1, xo, tpo);
    }
}

extern "C" void kernel_launch(void* const* d_in, const int* in_sizes, int n_in,
                              void* d_out, int out_size, void* d_ws, size_t ws_size,
                              hipStream_t stream) {
    const float* x    = (const float*)d_in[0];
    const float* tim  = (const float*)d_in[1];
    const float* Wih  = (const float*)d_in[2];
    const float* Whh  = (const float*)d_in[3];
    const float* bias = (const float*)d_in[4];
    const float* h0   = (const float*)d_in[5];
    const float* c0   = (const float*)d_in[6];

    u64* hbuf = (u64*)d_ws;

    // tags must start != any wanted tag every launch (graph replays included)
    hipMemsetAsync(d_ws, 0, GRPS * 2 * 1024 * sizeof(u64), stream);

    lstm_grp2<<<GRPS * WPG, NTHR, 0, stream>>>(x, tim, Wih, Whh, bias, h0, c0,
                                               (float*)d_out, hbuf);
}

// Round 10
// 7932.264 us; speedup vs baseline: 1.3704x; 1.0089x over previous
//
#include <hip/hip_runtime.h>

#define TS    2048
#define BTOT  32
#define IDIM  256
#define HDIM  512
#define GRPS  8      // batch groups (4 batches each); h exchanged only in-group
#define WPG   32     // WGs per group: 64 gate cols each (16 h-cols x 4 gates)
#define BPG   4
#define NTHR  256    // 4 waves; wave wv = gate wv (N-split, full K)
#define KX    8      // x k-frags (K=256)
#define KT    24     // + 16 h k-frags (K=512)

typedef __attribute__((ext_vector_type(8))) short    bfrag;  // 8 bf16
typedef __attribute__((ext_vector_type(4))) float    facc;   // 4 f32
typedef unsigned long long u64;

#define LD_A64(p)   __hip_atomic_load((p),  __ATOMIC_RELAXED, __HIP_MEMORY_SCOPE_AGENT)
#define ST_A64(p,v) __hip_atomic_store((p),(v),__ATOMIC_RELAXED, __HIP_MEMORY_SCOPE_AGENT)

__device__ __forceinline__ unsigned short f2bf(float f){
    unsigned u = __builtin_bit_cast(unsigned, f);
    u += 0x7FFFu + ((u >> 16) & 1u);            // RNE
    return (unsigned short)(u >> 16);
}
__device__ __forceinline__ unsigned pack2(float a, float b){
    return (unsigned)f2bf(a) | ((unsigned)f2bf(b) << 16);
}

// R5 skeleton (6.78 ms champion) + ONLY verified deltas:
//  (1) R7/R8/R9-verified 0-conflict LDS hstage swizzle (parity double buffer):
//      write byte = row*1024 + ((chunk*16) ^ (row<<5))
//      read  byte = hrdbase ^ (j*64),  hrdbase = lb*1024 + ((kgrp*16)^(lb<<5))
//      (XOR on the FULL offset: (row<<5) bit6 overlaps j*64 — R6 lesson.)
//  (2) 4 MFMA accumulator chains (dep depth 16->4 on the post-barrier path).
//  NO s_sleep in the retry loop (R9: sleep on the detection path cost +1.2ms).
// Protocol unchanged: self-timestamped u64 words (tag<<32 | 2xbf16), parity
// double buffer, per-word register snapshots; overwrite safety via B1-chain
// (see R5 notes). hbuf memset each launch -> graph replays deterministic.

#define LSTM_STEP(Tt, XF, TPF)                                                  \
  do {                                                                          \
    facc acc[4];                                                                \
    _Pragma("unroll")                                                           \
    for (int q = 0; q < 4; ++q) acc[q] = (facc){0.f,0.f,0.f,0.f};               \
    /* x-GEMM overlaps the in-flight tagged h loads (issued last tail) */       \
    _Pragma("unroll")                                                           \
    for (int j = 0; j < KX; ++j)                                                \
      acc[j & 3] = __builtin_amdgcn_mfma_f32_16x16x32_bf16(XF[j], breg[j],      \
                                                           acc[j & 3], 0,0,0); \
    /* tag check + hot-spin retry (matched words keep register snapshot) */     \
    { const unsigned want = (unsigned)(Tt) + 1u;                                \
      while ((((unsigned)(w0 >> 32) != want) | ((unsigned)(w1 >> 32) != want) | \
              ((unsigned)(w2 >> 32) != want) | ((unsigned)(w3 >> 32) != want))  \
             != 0u){                                                            \
        if ((unsigned)(w0 >> 32) != want) w0 = LD_A64(hsrc + 0);                \
        if ((unsigned)(w1 >> 32) != want) w1 = LD_A64(hsrc + 1);                \
        if ((unsigned)(w2 >> 32) != want) w2 = LD_A64(hsrc + 2);                \
        if ((unsigned)(w3 >> 32) != want) w3 = LD_A64(hsrc + 3);                \
      } }                                                                       \
    /* stage h into swizzled LDS (parity double buffer) */                      \
    { uint4 pv; pv.x = (unsigned)w0; pv.y = (unsigned)w1;                       \
      pv.z = (unsigned)w2; pv.w = (unsigned)w3;                                 \
      *reinterpret_cast<uint4*>(                                                \
          reinterpret_cast<char*>(&hstage[(Tt) & 1][0][0]) + stoff) = pv; }     \
    __syncthreads();                                  /* B1: h staged */        \
    /* h-GEMM: 0-conflict swizzled b128 reads, 4 chains */                      \
    { const char* hb8 =                                                         \
          reinterpret_cast<const char*>(&hstage[(Tt) & 1][0][0]);               \
      _Pragma("unroll")                                                         \
      for (int jj = 0; jj < 16; ++jj){                                          \
        const bfrag hf = *reinterpret_cast<const bfrag*>(                       \
            hb8 + (hrdbase ^ (jj * 64)));                                       \
        acc[jj & 3] = __builtin_amdgcn_mfma_f32_16x16x32_bf16(hf, breg[KX+jj],  \
                                                              acc[jj & 3],     \
                                                              0,0,0);          \
      } }                                                                       \
    const facc zz = (acc[0] + acc[1]) + (acc[2] + acc[3]);                      \
    if (lane < 16){   /* D rows 0..3 = batches (rows 4..15 junk, never read) */ \
      _Pragma("unroll")                                                         \
      for (int q = 0; q < 4; ++q) zfull[wv][q][lane] = zz[q];                   \
    }                                                                           \
    __syncthreads();                                  /* B2: z ready */         \
    float hn0 = 0.f, hn1 = 0.f;                                                 \
    if (gth){                                                                   \
      float zg0[4], zg1[4];                                                     \
      _Pragma("unroll")                                                         \
      for (int gt = 0; gt < 4; ++gt){                                           \
        zg0[gt] = zfull[gt][b][col0]     + bs2[gt][0] + wt2[gt][0] * (TPF);     \
        zg1[gt] = zfull[gt][b][col0 + 1] + bs2[gt][1] + wt2[gt][1] * (TPF);     \
      }                                                                         \
      { const float ig = 1.f/(1.f+__expf(-zg0[0]));                             \
        const float fg = 1.f/(1.f+__expf(-zg0[1]));                             \
        const float gg = 1.f - 2.f/(__expf(2.f*zg0[2])+1.f);                    \
        const float og = 1.f/(1.f+__expf(-zg0[3]));                             \
        creg0 = fg*creg0 + ig*gg;                                               \
        hn0 = og*(1.f - 2.f/(__expf(2.f*creg0)+1.f)); }                         \
      { const float ig = 1.f/(1.f+__expf(-zg1[0]));                             \
        const float fg = 1.f/(1.f+__expf(-zg1[1]));                             \
        const float gg = 1.f - 2.f/(__expf(2.f*zg1[2])+1.f);                    \
        const float og = 1.f/(1.f+__expf(-zg1[3]));                             \
        creg1 = fg*creg1 + ig*gg;                                               \
        hn1 = og*(1.f - 2.f/(__expf(2.f*creg1)+1.f)); }                         \
      ST_A64(hgrp + (size_t)(((Tt)+1) & 1) * 1024 + b*256 + r*8 + cp,           \
             ((u64)((unsigned)(Tt) + 2u) << 32) | (u64)pack2(hn0, hn1));        \
    }                                                                           \
    /* ---- tail: issue next h loads FIRST (FIFO), then x, then out ---- */     \
    { const int tn = ((Tt)+2 < TS) ? ((Tt)+2) : (TS-1);                         \
      hsrc = hgrp + (size_t)(((Tt) + 1) & 1) * 1024 + (size_t)tid * 4;          \
      w0 = LD_A64(hsrc + 0); w1 = LD_A64(hsrc + 1);                             \
      w2 = LD_A64(hsrc + 2); w3 = LD_A64(hsrc + 3);                             \
      if (ldr){                                                                 \
        _Pragma("unroll")                                                       \
        for (int j = 0; j < KX; ++j){                                           \
          const float4* p4 = reinterpret_cast<const float4*>(                   \
              x + ((size_t)tn*BTOT + lbg)*IDIM + j*32 + kgrp*8);                \
          const float4 f0 = p4[0], f1 = p4[1];                                  \
          bfrag v;                                                              \
          v[0]=(short)f2bf(f0.x); v[1]=(short)f2bf(f0.y);                       \
          v[2]=(short)f2bf(f0.z); v[3]=(short)f2bf(f0.w);                       \
          v[4]=(short)f2bf(f1.x); v[5]=(short)f2bf(f1.y);                       \
          v[6]=(short)f2bf(f1.z); v[7]=(short)f2bf(f1.w);                       \
          XF[j] = v;                                                            \
        }                                                                       \
      }                                                                         \
      if (gth){                                                                 \
        (TPF) = tim[(size_t)tn * BTOT + bglob];                                 \
        *reinterpret_cast<float2*>(                                             \
            &out[((size_t)(Tt) * BTOT + bglob) * HDIM + hcol0]) =               \
            make_float2(hn0, hn1);                                              \
        if ((Tt) == TS - 1){                                                    \
          float* hT = out + (size_t)TS * BTOT * HDIM;                           \
          float* cT = hT + (size_t)BTOT * HDIM;                                 \
          *reinterpret_cast<float2*>(&hT[(size_t)bglob * HDIM + hcol0]) =       \
              make_float2(hn0, hn1);                                            \
          *reinterpret_cast<float2*>(&cT[(size_t)bglob * HDIM + hcol0]) =       \
              make_float2(creg0, creg1);                                        \
        }                                                                       \
      }                                                                         \
    }                                                                           \
  } while(0)

__global__ __launch_bounds__(NTHR, 1) void lstm_grp3(
    const float* __restrict__ x,      // [T,B,I]
    const float* __restrict__ tim,    // [T,B,1]
    const float* __restrict__ Wih,    // [4H, I+1]
    const float* __restrict__ Whh,    // [4H, H]
    const float* __restrict__ bias,   // [4H]
    const float* __restrict__ h0,     // [B,H]
    const float* __restrict__ c0,     // [B,H]
    float* __restrict__ out,          // [T,B,H] ++ [B,H] ++ [B,H]
    u64* __restrict__ hbuf)           // [GRPS][2][1024] tagged words
{
    const int tid = threadIdx.x, bid = blockIdx.x;
    const int g = bid & 7, r = bid >> 3;           // group, 16-col role
    const int wv = tid >> 6, lane = tid & 63, l15 = lane & 15, kgrp = lane >> 4;

    __shared__ unsigned short hstage[2][4][512];   // 8 KB, swizzled (verified)
    __shared__ float zfull[4][4][16];              // [gate][b][col]

    u64* hgrp = hbuf + (size_t)g * 2048;

    // ---- weights in registers: wave wv = gate wv, cols r*16+l15, full K ----
    bfrag breg[KT];
    {
        const int colg = wv * HDIM + r * 16 + l15;
        #pragma unroll
        for (int j = 0; j < KT; ++j){
            const float* src = (j < KX)
                ? (Wih + (size_t)colg * (IDIM + 1) + j * 32 + kgrp * 8)
                : (Whh + (size_t)colg * HDIM + (j - KX) * 32 + kgrp * 8);
            bfrag v;
            #pragma unroll
            for (int q = 0; q < 8; ++q) v[q] = (short)f2bf(src[q]);
            breg[j] = v;
        }
    }

    // ---- gate threads (tid<32): item (b, col0=2*cp, col0+1) ----
    const bool gth = (tid < 32);
    const int b = (tid >> 3) & 3, cp = tid & 7, col0 = cp * 2;
    const int hcol0 = r * 16 + col0, bglob = g * BPG + b;
    float bs2[4][2], wt2[4][2];
    float creg0 = 0.f, creg1 = 0.f;
    if (gth){
        #pragma unroll
        for (int gt = 0; gt < 4; ++gt){
            const size_t cg = (size_t)gt * HDIM + hcol0;
            bs2[gt][0] = bias[cg];     bs2[gt][1] = bias[cg + 1];
            wt2[gt][0] = Wih[cg * (IDIM + 1) + IDIM];
            wt2[gt][1] = Wih[(cg + 1) * (IDIM + 1) + IDIM];
        }
        creg0 = c0[(size_t)bglob * HDIM + hcol0];
        creg1 = c0[(size_t)bglob * HDIM + hcol0 + 1];
        // publish h(0): parity 0, tag 1
        ST_A64(hgrp + 0 * 1024 + b * 256 + r * 8 + cp,
               (1ULL << 32) | (u64)pack2(h0[(size_t)bglob * HDIM + hcol0],
                                         h0[(size_t)bglob * HDIM + hcol0 + 1]));
    } else {
        #pragma unroll
        for (int gt = 0; gt < 4; ++gt){
            bs2[gt][0] = bs2[gt][1] = wt2[gt][0] = wt2[gt][1] = 0.f;
        }
    }

    // ---- staging / read offsets (verified 0-conflict swizzle) ----
    const int swb   = tid >> 6;                     // staged batch row
    const int stoff = swb * 1024 + (((tid & 63) * 16) ^ (swb << 5));
    const int lb    = l15 & 3;                      // A-row batch
    const int hrdbase = lb * 1024 + ((kgrp * 16) ^ (lb << 5));

    // ---- A-loader lanes for x (rows 0..3 real, 4..15 junk) ----
    const bool ldr = (l15 < 4);
    const int lbg = g * BPG + lb;

    // ---- issue initial tagged loads (parity 0) BEFORE the x prefetch ----
    const u64* hsrc = hgrp + (size_t)tid * 4;
    u64 w0 = LD_A64(hsrc + 0), w1 = LD_A64(hsrc + 1);
    u64 w2 = LD_A64(hsrc + 2), w3 = LD_A64(hsrc + 3);

    // ---- x prefetch x(0)->xe, x(1)->xo (bf16, registers); time prefetch ----
    bfrag xe[KX], xo[KX];
    #pragma unroll
    for (int j = 0; j < KX; ++j){
        bfrag zv;
        #pragma unroll
        for (int q = 0; q < 8; ++q) zv[q] = 0;
        xe[j] = zv; xo[j] = zv;
    }
    if (ldr){
        #pragma unroll
        for (int j = 0; j < KX; ++j){
            const float4* p0 = reinterpret_cast<const float4*>(
                x + ((size_t)0 * BTOT + lbg) * IDIM + j * 32 + kgrp * 8);
            const float4* p1 = reinterpret_cast<const float4*>(
                x + ((size_t)1 * BTOT + lbg) * IDIM + j * 32 + kgrp * 8);
            const float4 a0 = p0[0], a1 = p0[1], b0 = p1[0], b1 = p1[1];
            bfrag v;
            v[0]=(short)f2bf(a0.x); v[1]=(short)f2bf(a0.y);
            v[2]=(short)f2bf(a0.z); v[3]=(short)f2bf(a0.w);
            v[4]=(short)f2bf(a1.x); v[5]=(short)f2bf(a1.y);
            v[6]=(short)f2bf(a1.z); v[7]=(short)f2bf(a1.w);
            xe[j] = v;
            bfrag w;
            w[0]=(short)f2bf(b0.x); w[1]=(short)f2bf(b0.y);
            w[2]=(short)f2bf(b0.z); w[3]=(short)f2bf(b0.w);
            w[4]=(short)f2bf(b1.x); w[5]=(short)f2bf(b1.y);
            w[6]=(short)f2bf(b1.z); w[7]=(short)f2bf(b1.w);
            xo[j] = w;
        }
    }
    float tpe = 0.f, tpo = 0.f;
    if (gth){
        tpe = tim[(size_t)0 * BTOT + bglob];
        tpo = tim[(size_t)1 * BTOT + bglob];
    }

    for (int t = 0; t < TS; t += 2){
        LSTM_STEP(t,     xe, tpe);
        LSTM_STEP(t + 1, xo, tpo);
    }
}

extern "C" void kernel_launch(void* const* d_in, const int* in_sizes, int n_in,
                              void* d_out, int out_size, void* d_ws, size_t ws_size,
                              hipStream_t stream) {
    const float* x    = (const float*)d_in[0];
    const float* tim  = (const float*)d_in[1];
    const float* Wih  = (const float*)d_in[2];
    const float* Whh  = (const float*)d_in[3];
    const float* bias = (const float*)d_in[4];
    const float* h0   = (const float*)d_in[5];
    const float* c0   = (const float*)d_in[6];

    u64* hbuf = (u64*)d_ws;

    // tags must start != any wanted tag every launch (graph replays included)
    hipMemsetAsync(d_ws, 0, GRPS * 2 * 1024 * sizeof(u64), stream);

    lstm_grp3<<<GRPS * WPG, NTHR, 0, stream>>>(x, tim, Wih, Whh, bias, h0, c0,
                                               (float*)d_out, hbuf);
}